// Round 5
// baseline (1218.675 us; speedup 1.0000x reference)
//
#include <hip/hip_runtime.h>
#include <math.h>

// Problem constants (match reference)
constexpr int CH         = 64;
constexpr int N_USERS    = 50000;
constexpr int N_ENTITIES = 100000;
constexpr int N_FACTORS  = 4;
constexpr int N_RELM1    = 8;     // N_REL - 1
constexpr int N_EDGES    = 1500000;
constexpr int NNZ        = 800000;

constexpr int NBE        = (N_ENTITIES + 255) / 256;  // 391 buckets/scan blocks (E)
constexpr int NBU        = (N_USERS + 255) / 256;     // 196 buckets/scan blocks (U)
constexpr int TOTAL      = N_EDGES + NNZ;             // 2.3M items
constexpr int ENT_BLOCKS = N_ENTITIES / 4;            // 25000 (exact)
constexpr int USR_BLOCKS = N_USERS / 4;               // 12500 (exact)

// ---------------------------------------------------------------------------
__device__ __forceinline__ float waveReduceSum(float v) {
    #pragma unroll
    for (int off = 32; off > 0; off >>= 1)
        v += __shfl_xor(v, off, 64);
    return v;
}

// ---------------------------------------------------------------------------
// Fused histogram: items [0,N_EDGES) -> cntE[head], rest -> cntU[irows].
__global__ __launch_bounds__(256)
void hist_all(const int* __restrict__ head, const int* __restrict__ irows,
              int* __restrict__ cntE, int* __restrict__ cntU) {
    int t  = blockIdx.x * 256 + threadIdx.x;
    int NT = gridDim.x * 256;
    int  k[4]; bool val[4], isE[4];
    #pragma unroll
    for (int j = 0; j < 4; ++j) {
        int i = t + j * NT;
        val[j] = i < TOTAL;
        isE[j] = i < N_EDGES;
        k[j] = 0;
        if (val[j]) k[j] = isE[j] ? head[i] : irows[i - N_EDGES];
    }
    #pragma unroll
    for (int j = 0; j < 4; ++j)
        if (val[j]) atomicAdd(isE[j] ? &cntE[k[j]] : &cntU[k[j]], 1);
}

// ---------------------------------------------------------------------------
// Scan pass 1: per-block exclusive scan of cntE/cntU; emit block sums.
__global__ __launch_bounds__(256)
void scan_partial(const int* __restrict__ cntE, const int* __restrict__ cntU,
                  int* __restrict__ offE, int* __restrict__ offU,
                  int* __restrict__ bsum) {
    __shared__ int lds[256];
    int b = blockIdx.x;
    const int* src; int* dst; int n, lb;
    if (b < NBE) { src = cntE; dst = offE; n = N_ENTITIES; lb = b; }
    else         { src = cntU; dst = offU; n = N_USERS;    lb = b - NBE; }
    int gid = lb * 256 + threadIdx.x;
    int v = (gid < n) ? src[gid] : 0;
    lds[threadIdx.x] = v;
    __syncthreads();
    for (int d = 1; d < 256; d <<= 1) {
        int u = (threadIdx.x >= d) ? lds[threadIdx.x - d] : 0;
        __syncthreads();
        lds[threadIdx.x] += u;
        __syncthreads();
    }
    if (gid < n) dst[gid] = lds[threadIdx.x] - v;
    if (threadIdx.x == 255) bsum[b] = lds[255];
}

// Scan pass 2: block 0 scans bsum[0..NBE), block 1 scans bsum[NBE..NBE+NBU).
__global__ __launch_bounds__(512)
void scan_bsums(int* __restrict__ bsum) {
    __shared__ int lds[512];
    int base = (blockIdx.x == 0) ? 0   : NBE;
    int nb   = (blockIdx.x == 0) ? NBE : NBU;
    int v = (threadIdx.x < nb) ? bsum[base + threadIdx.x] : 0;
    lds[threadIdx.x] = v;
    __syncthreads();
    for (int d = 1; d < 512; d <<= 1) {
        int u = (threadIdx.x >= d) ? lds[threadIdx.x - d] : 0;
        __syncthreads();
        lds[threadIdx.x] += u;
        __syncthreads();
    }
    if (threadIdx.x < nb) bsum[base + threadIdx.x] = lds[threadIdx.x] - v;
}

// Scan pass 3: add block offsets, write off[], off[n]=total, and init the
// coarse-bucket staging cursors (ccur[b] = off[first key of bucket b]).
__global__ __launch_bounds__(256)
void add_offsets(int* __restrict__ offE, int* __restrict__ offU,
                 const int* __restrict__ bsum, int* __restrict__ ccur) {
    int b = blockIdx.x;
    int* off; int n, lb, total;
    if (b < NBE) { off = offE; n = N_ENTITIES; lb = b;       total = N_EDGES; }
    else         { off = offU; n = N_USERS;    lb = b - NBE; total = NNZ; }
    int gid = lb * 256 + threadIdx.x;
    int o = 0;
    if (gid < n) {
        o = off[gid] + bsum[b];
        off[gid] = o;
    }
    if (threadIdx.x == 0) ccur[b] = o;      // gid = lb*256 < n always here
    if (gid == n) off[n] = total;
}

// ---------------------------------------------------------------------------
// Phase B: partition items into coarse 256-key buckets. Staging regions are
// the final CSR sub-ranges [off[b*256], off[(b+1)*256]) so appends cluster.
__global__ __launch_bounds__(256)
void scatter_stage(const int* __restrict__ head, const int* __restrict__ tail,
                   const int* __restrict__ etype,
                   const int* __restrict__ irows, const int* __restrict__ icols,
                   const float* __restrict__ ivals,
                   int* __restrict__ ccur,
                   int2* __restrict__ stageE, int2* __restrict__ stageUkc,
                   float* __restrict__ stageUv) {
    int t  = blockIdx.x * 256 + threadIdx.x;
    int NT = gridDim.x * 256;
    int key[4], pay[4]; float pv[4]; bool val[4], isE[4];
    #pragma unroll
    for (int j = 0; j < 4; ++j) {
        int i = t + j * NT;
        val[j] = i < TOTAL;
        isE[j] = i < N_EDGES;
        key[j] = 0; pay[j] = 0; pv[j] = 0.0f;
        if (val[j]) {
            if (isE[j]) { key[j] = head[i]; pay[j] = tail[i] | ((etype[i] - 1) << 20); }
            else { int ii = i - N_EDGES; key[j] = irows[ii]; pay[j] = icols[ii]; pv[j] = ivals[ii]; }
        }
    }
    #pragma unroll
    for (int j = 0; j < 4; ++j) {
        if (!val[j]) continue;
        if (isE[j]) {
            int b = key[j] >> 8;
            int pos = atomicAdd(&ccur[b], 1);
            stageE[pos] = make_int2(key[j], pay[j]);
        } else {
            int b = NBE + (key[j] >> 8);
            int pos = atomicAdd(&ccur[b], 1);
            stageUkc[pos] = make_int2(key[j], pay[j]);
            stageUv[pos]  = pv[j];
        }
    }
}

// Phase C: one block per bucket; LDS fine-key cursors; coalesced staged reads;
// final CSR writes land in the bucket's contiguous (L2-resident) range.
__global__ __launch_bounds__(256)
void bin_fill(const int* __restrict__ offE, const int* __restrict__ offU,
              const int2* __restrict__ stageE, const int2* __restrict__ stageUkc,
              const float* __restrict__ stageUv,
              int* __restrict__ elst, int* __restrict__ ucol,
              float* __restrict__ uval) {
    __shared__ int cur[256];
    int b = blockIdx.x;
    if (b < NBE) {
        int base = b * 256;
        int kidx = base + threadIdx.x;
        cur[threadIdx.x] = (kidx < N_ENTITIES) ? offE[kidx] : 0;
        __syncthreads();
        int lo = offE[base];
        int hi = offE[min(base + 256, N_ENTITIES)];
        for (int i = lo + threadIdx.x; i < hi; i += 256) {
            int2 s = stageE[i];
            int p = atomicAdd(&cur[s.x & 255], 1);
            elst[p] = s.y;
        }
    } else {
        int base = (b - NBE) * 256;
        int kidx = base + threadIdx.x;
        cur[threadIdx.x] = (kidx < N_USERS) ? offU[kidx] : 0;
        __syncthreads();
        int lo = offU[base];
        int hi = offU[min(base + 256, N_USERS)];
        for (int i = lo + threadIdx.x; i < hi; i += 256) {
            int2 s = stageUkc[i];
            float v = stageUv[i];
            int p = atomicAdd(&cur[s.x & 255], 1);
            ucol[p] = s.y;
            uval[p] = v;
        }
    }
}

// ---------------------------------------------------------------------------
// Fused per-hop pass: blocks [0,ENT_BLOCKS) do entity rows, rest do users.
template <bool HOP0>
__global__ __launch_bounds__(256)
void hop_pass(const float* __restrict__ ent_in, const float* __restrict__ usr_in,
              const float* __restrict__ weight, const float* __restrict__ latent,
              const float* __restrict__ dw,
              const int* __restrict__ offE, const int* __restrict__ elst,
              const int* __restrict__ offU, const int* __restrict__ ucol,
              const float* __restrict__ uval,
              float* __restrict__ Ae_out, float* __restrict__ Au_out,
              float* __restrict__ ent_res, float* __restrict__ usr_res,
              const float* __restrict__ ent_base, const float* __restrict__ usr_base) {
    __shared__ float w_lds[N_RELM1 * CH];
    int lane = threadIdx.x & 63;
    if (blockIdx.x < ENT_BLOCKS) {
        for (int i = threadIdx.x; i < N_RELM1 * CH; i += 256) w_lds[i] = weight[i];
        __syncthreads();
        int row = blockIdx.x * 4 + (threadIdx.x >> 6);
        int lo = offE[row], hi = offE[row + 1];
        float acc = 0.0f;
        for (int k0 = lo; k0 < hi; k0 += 64) {
            int m = min(64, hi - k0);
            int p = (lane < m) ? elst[k0 + lane] : 0;
            int k = 0;
            for (; k + 3 < m; k += 4) {      // 4 gathers in flight
                int p0 = __shfl(p, k,     64);
                int p1 = __shfl(p, k + 1, 64);
                int p2 = __shfl(p, k + 2, 64);
                int p3 = __shfl(p, k + 3, 64);
                float x0 = ent_in[(p0 & 0xFFFFF) * CH + lane];
                float x1 = ent_in[(p1 & 0xFFFFF) * CH + lane];
                float x2 = ent_in[(p2 & 0xFFFFF) * CH + lane];
                float x3 = ent_in[(p3 & 0xFFFFF) * CH + lane];
                acc += x0 * w_lds[(p0 >> 20) * CH + lane];
                acc += x1 * w_lds[(p1 >> 20) * CH + lane];
                acc += x2 * w_lds[(p2 >> 20) * CH + lane];
                acc += x3 * w_lds[(p3 >> 20) * CH + lane];
            }
            for (; k < m; ++k) {
                int pk = __shfl(p, k, 64);
                acc += ent_in[(pk & 0xFFFFF) * CH + lane] * w_lds[(pk >> 20) * CH + lane];
            }
        }
        float s = waveReduceSum(acc * acc);
        float y = acc / fmaxf(sqrtf(s), 1e-12f);
        int idx = row * CH + lane;
        if (HOP0) { Ae_out[idx] = y; ent_res[idx] = ent_base[idx] + y; }
        else      { ent_res[idx] += y; }
    } else {
        int row = (blockIdx.x - ENT_BLOCKS) * 4 + (threadIdx.x >> 6);
        int idx = row * CH + lane;
        float u  = usr_in[idx];
        float d0 = waveReduceSum(u * latent[0 * CH + lane]);
        float d1 = waveReduceSum(u * latent[1 * CH + lane]);
        float d2 = waveReduceSum(u * latent[2 * CH + lane]);
        float d3 = waveReduceSum(u * latent[3 * CH + lane]);
        float mx = fmaxf(fmaxf(d0, d1), fmaxf(d2, d3));
        float e0 = expf(d0 - mx), e1 = expf(d1 - mx), e2 = expf(d2 - mx), e3 = expf(d3 - mx);
        float inv = 1.0f / (e0 + e1 + e2 + e3);
        float mix = (e0 * dw[0 * CH + lane] + e1 * dw[1 * CH + lane] +
                     e2 * dw[2 * CH + lane] + e3 * dw[3 * CH + lane]) * inv;
        float acc = 0.0f;
        int lo = offU[row], hi = offU[row + 1];
        for (int k0 = lo; k0 < hi; k0 += 64) {
            int m = min(64, hi - k0);
            int   cl = (lane < m) ? ucol[k0 + lane] : 0;
            float vv = (lane < m) ? uval[k0 + lane] : 0.0f;
            int k = 0;
            for (; k + 3 < m; k += 4) {
                int   c0 = __shfl(cl, k,     64);
                int   c1 = __shfl(cl, k + 1, 64);
                int   c2 = __shfl(cl, k + 2, 64);
                int   c3 = __shfl(cl, k + 3, 64);
                float v0 = __shfl(vv, k,     64);
                float v1 = __shfl(vv, k + 1, 64);
                float v2 = __shfl(vv, k + 2, 64);
                float v3 = __shfl(vv, k + 3, 64);
                float x0 = ent_in[c0 * CH + lane];
                float x1 = ent_in[c1 * CH + lane];
                float x2 = ent_in[c2 * CH + lane];
                float x3 = ent_in[c3 * CH + lane];
                acc += v0 * x0; acc += v1 * x1; acc += v2 * x2; acc += v3 * x3;
            }
            for (; k < m; ++k) {
                int   ck = __shfl(cl, k, 64);
                float vk = __shfl(vv, k, 64);
                acc += vk * ent_in[ck * CH + lane];
            }
        }
        float un = acc * (1.0f + mix);
        float s  = waveReduceSum(un * un);
        float y  = un / fmaxf(sqrtf(s), 1e-12f);
        if (HOP0) { Au_out[idx] = y; usr_res[idx] = usr_base[idx] + y; }
        else      { usr_res[idx] += y; }
    }
}

// ---------------------------------------------------------------------------
// Block 0: disen_weight = softmax(att,-1) @ weight (4x8 @ 8x64).
// Block 1: distance-correlation, one wave per factor pair, lane = (r,c) of 8x8.
__global__ __launch_bounds__(384)
void discor_kernel(const float* __restrict__ att,
                   const float* __restrict__ weight,
                   float* __restrict__ dw,
                   float* __restrict__ cor_out) {
    __shared__ float part[6];
    if (blockIdx.x == 0) {
        if (threadIdx.x < 256) {
            int f = threadIdx.x >> 6;
            int c = threadIdx.x & 63;
            float m = -1e30f;
            #pragma unroll
            for (int j = 0; j < N_RELM1; ++j) m = fmaxf(m, att[f * N_RELM1 + j]);
            float s = 0.0f, w[N_RELM1];
            #pragma unroll
            for (int j = 0; j < N_RELM1; ++j) { w[j] = expf(att[f * N_RELM1 + j] - m); s += w[j]; }
            float acc = 0.0f;
            #pragma unroll
            for (int j = 0; j < N_RELM1; ++j) acc += w[j] * weight[j * CH + c];
            dw[f * CH + c] = acc / s;
        }
    } else {
        int w    = threadIdx.x >> 6;   // 0..5 = pair index
        int lane = threadIdx.x & 63;
        const int pi[6] = {0, 0, 0, 1, 1, 2};
        const int pj[6] = {1, 2, 3, 2, 3, 3};
        int r = lane >> 3, c = lane & 7;
        const float* t1 = att + pi[w] * N_RELM1;
        const float* t2 = att + pj[w] * N_RELM1;
        float a  = sqrtf(fmaxf(t1[r] * t1[r] - 2.0f * t1[r] * t1[c] + t1[c] * t1[c], 0.0f) + 1e-8f);
        float bb = sqrtf(fmaxf(t2[r] * t2[r] - 2.0f * t2[r] * t2[c] + t2[c] * t2[c], 0.0f) + 1e-8f);
        float rsA = a, rsB = bb;
        #pragma unroll
        for (int o = 1; o < 8; o <<= 1) { rsA += __shfl_xor(rsA, o, 64); rsB += __shfl_xor(rsB, o, 64); }
        float csA = a, csB = bb;
        #pragma unroll
        for (int o = 8; o < 64; o <<= 1) { csA += __shfl_xor(csA, o, 64); csB += __shfl_xor(csB, o, 64); }
        float totA = rsA, totB = rsB;
        #pragma unroll
        for (int o = 8; o < 64; o <<= 1) { totA += __shfl_xor(totA, o, 64); totB += __shfl_xor(totB, o, 64); }
        float A = a  - csA * 0.125f - rsA * 0.125f + totA * (1.0f / 64.0f);
        float B = bb - csB * 0.125f - rsB * 0.125f + totB * (1.0f / 64.0f);
        float sAB = A * B, sAA = A * A, sBB = B * B;
        #pragma unroll
        for (int o = 1; o < 64; o <<= 1) {
            sAB += __shfl_xor(sAB, o, 64);
            sAA += __shfl_xor(sAA, o, 64);
            sBB += __shfl_xor(sBB, o, 64);
        }
        if (lane == 0) {
            float dAB = sqrtf(fmaxf(sAB * (1.0f / 64.0f), 0.0f) + 1e-8f);
            float dAA = sqrtf(fmaxf(sAA * (1.0f / 64.0f), 0.0f) + 1e-8f);
            float dBB = sqrtf(fmaxf(sBB * (1.0f / 64.0f), 0.0f) + 1e-8f);
            part[w] = dAB / sqrtf(dAA * dBB + 1e-8f);
        }
        __syncthreads();
        if (threadIdx.x == 0) {
            float s = 0.0f;
            for (int q = 0; q < 6; ++q) s += part[q];
            cor_out[0] = s;
        }
    }
}

// ---------------------------------------------------------------------------
extern "C" void kernel_launch(void* const* d_in, const int* in_sizes, int n_in,
                              void* d_out, int out_size, void* d_ws, size_t ws_size,
                              hipStream_t stream) {
    const float* user_emb   = (const float*)d_in[0];
    const float* entity_emb = (const float*)d_in[1];
    const float* latent     = (const float*)d_in[2];
    const float* weight     = (const float*)d_in[3];
    const float* att        = (const float*)d_in[4];
    const float* ivals      = (const float*)d_in[5];
    const int*   head       = (const int*)d_in[6];
    const int*   tail       = (const int*)d_in[7];
    const int*   etype      = (const int*)d_in[8];
    const int*   irows      = (const int*)d_in[9];
    const int*   icols      = (const int*)d_in[10];

    float* out     = (float*)d_out;
    float* ent_res = out;
    float* usr_res = out + (size_t)N_ENTITIES * CH;
    float* cor_out = out + (size_t)N_ENTITIES * CH + (size_t)N_USERS * CH;

    const size_t ENT_ELEMS = (size_t)N_ENTITIES * CH;   // 6.4M
    const size_t USR_ELEMS = (size_t)N_USERS * CH;      // 3.2M

    // Workspace carve-up (~52 MB). Staging aliases Ae (dead until hop 0).
    float* ws   = (float*)d_ws;
    float* Ae   = ws;                               // entity emb after hop0 (25.6 MB)
    float* Au   = Ae + ENT_ELEMS;                   // user emb after hop0 (12.8 MB)
    float* dw   = Au + USR_ELEMS;                   // 4x64 disen weight
    int*   cntE = (int*)(dw + N_FACTORS * CH);      // 100000 (one memset w/ cntU)
    int*   cntU = cntE + N_ENTITIES;                // 50000
    int*   offE = cntU + N_USERS;                   // 100001
    int*   offU = offE + N_ENTITIES + 1;            // 50001
    int*   bsum = offU + N_USERS + 1;               // 1024 (NBE+NBU=587)
    int*   ccur = bsum + 1024;                      // 1024 coarse cursors
    int*   elst = ccur + 1024;                      // 1.5M packed
    int*   ucol = elst + N_EDGES;                   // 800K
    float* uval = (float*)(ucol + NNZ);             // 800K
    // Staging aliased on Ae: 1.5M int2 + 800K int2 + 800K float = 21.6 MB < 25.6 MB
    int2*  stageE   = (int2*)Ae;
    int2*  stageUkc = ((int2*)Ae) + N_EDGES;
    float* stageUv  = (float*)(stageUkc + NNZ);

    // Zero only the histograms (single contiguous memset).
    hipMemsetAsync(cntE, 0, (N_ENTITIES + N_USERS) * sizeof(int), stream);

    discor_kernel<<<2, 384, 0, stream>>>(att, weight, dw, cor_out);

    // ---- Build CSR (shared by both hops) ----
    const int hb = (TOTAL + 1023) / 1024;   // 4 items/thread
    hist_all<<<hb, 256, 0, stream>>>(head, irows, cntE, cntU);
    scan_partial<<<NBE + NBU, 256, 0, stream>>>(cntE, cntU, offE, offU, bsum);
    scan_bsums<<<2, 512, 0, stream>>>(bsum);
    add_offsets<<<NBE + NBU, 256, 0, stream>>>(offE, offU, bsum, ccur);
    scatter_stage<<<hb, 256, 0, stream>>>(head, tail, etype, irows, icols, ivals,
                                          ccur, stageE, stageUkc, stageUv);
    bin_fill<<<NBE + NBU, 256, 0, stream>>>(offE, offU, stageE, stageUkc, stageUv,
                                            elst, ucol, uval);

    // ---- Hop 0 (reads input embeddings; writes Ae/Au — staging now dead) ----
    hop_pass<true><<<ENT_BLOCKS + USR_BLOCKS, 256, 0, stream>>>(
        entity_emb, user_emb, weight, latent, dw,
        offE, elst, offU, ucol, uval,
        Ae, Au, ent_res, usr_res, entity_emb, user_emb);

    // ---- Hop 1 (reads hop-0 embeddings) ----
    hop_pass<false><<<ENT_BLOCKS + USR_BLOCKS, 256, 0, stream>>>(
        Ae, Au, weight, latent, dw,
        offE, elst, offU, ucol, uval,
        nullptr, nullptr, ent_res, usr_res, nullptr, nullptr);
}

// Round 6
// 417.899 us; speedup vs baseline: 2.9162x; 2.9162x over previous
//
#include <hip/hip_runtime.h>
#include <math.h>

// Problem constants (match reference)
constexpr int CH         = 64;
constexpr int N_USERS    = 50000;
constexpr int N_ENTITIES = 100000;
constexpr int N_FACTORS  = 4;
constexpr int N_RELM1    = 8;     // N_REL - 1
constexpr int N_EDGES    = 1500000;
constexpr int NNZ        = 800000;

constexpr int NBE        = (N_ENTITIES + 255) / 256;  // 391 coarse buckets (E)
constexpr int NBU        = (N_USERS + 255) / 256;     // 196 coarse buckets (U)
constexpr int NBKT       = NBE + NBU;                 // 587
constexpr int TOTAL      = N_EDGES + NNZ;             // 2.3M items
constexpr int IPB        = 8192;                      // items per count/stage block
constexpr int NBLK       = (TOTAL + IPB - 1) / IPB;   // 281
constexpr int ENT_BLOCKS = N_ENTITIES / 4;            // 25000 (exact)
constexpr int USR_BLOCKS = N_USERS / 4;               // 12500 (exact)

// ---------------------------------------------------------------------------
__device__ __forceinline__ float waveReduceSum(float v) {
    #pragma unroll
    for (int off = 32; off > 0; off >>= 1)
        v += __shfl_xor(v, off, 64);
    return v;
}

__device__ __forceinline__ int coarse_bucket(int i, const int* __restrict__ head,
                                             const int* __restrict__ irows) {
    return (i < N_EDGES) ? (head[i] >> 8) : (NBE + (irows[i - N_EDGES] >> 8));
}

// ---------------------------------------------------------------------------
// A: per-block coarse-bucket histogram -> H[bucket * NBLK + block]. No global
// atomics; every H entry is written (incl. zeros), so no memset needed.
__global__ __launch_bounds__(256)
void count_coarse(const int* __restrict__ head, const int* __restrict__ irows,
                  int* __restrict__ H) {
    __shared__ int hist[NBKT];
    for (int j = threadIdx.x; j < NBKT; j += 256) hist[j] = 0;
    __syncthreads();
    int start = blockIdx.x * IPB;
    int end   = min(start + IPB, TOTAL);
    for (int i = start + threadIdx.x; i < end; i += 256)
        atomicAdd(&hist[coarse_bucket(i, head, irows)], 1);
    __syncthreads();
    for (int j = threadIdx.x; j < NBKT; j += 256)
        H[j * NBLK + blockIdx.x] = hist[j];
}

// B1: one wave per bucket — exclusive scan of H[bucket][0..NBLK) in place,
// bucket total -> T[bucket].
__global__ __launch_bounds__(64)
void scan_hcols(int* __restrict__ H, int* __restrict__ T) {
    int b = blockIdx.x, lane = threadIdx.x;
    int carry = 0;
    #pragma unroll
    for (int c = 0; c < (NBLK + 63) / 64; ++c) {
        int idx = c * 64 + lane;
        int v = (idx < NBLK) ? H[b * NBLK + idx] : 0;
        int incl = v;
        #pragma unroll
        for (int d = 1; d < 64; d <<= 1) {
            int u = __shfl_up(incl, d, 64);
            if (lane >= d) incl += u;
        }
        if (idx < NBLK) H[b * NBLK + idx] = carry + incl - v;
        carry += __shfl(incl, 63, 64);
    }
    if (lane == 0) T[b] = carry;
}

// B2: single block — exclusive scan of T[0..NBKT) -> Bb, sentinel Bb[NBKT].
__global__ __launch_bounds__(1024)
void scan_buckets(const int* __restrict__ T, int* __restrict__ Bb) {
    __shared__ int lds[1024];
    int t = threadIdx.x;
    int v = (t < NBKT) ? T[t] : 0;
    lds[t] = v;
    __syncthreads();
    for (int d = 1; d < 1024; d <<= 1) {
        int u = (t >= d) ? lds[t - d] : 0;
        __syncthreads();
        lds[t] += u;
        __syncthreads();
    }
    if (t < NBKT) Bb[t] = lds[t] - v;
    if (t == NBKT - 1) Bb[NBKT] = lds[t];
}

// ---------------------------------------------------------------------------
// C: partition items into coarse buckets. Each block's per-bucket range is
// pre-reserved (Bb[b] + H[b][blk]); allocation via LDS atomics only.
__global__ __launch_bounds__(256)
void scatter_stage(const int* __restrict__ head, const int* __restrict__ tail,
                   const int* __restrict__ etype,
                   const int* __restrict__ irows, const int* __restrict__ icols,
                   const float* __restrict__ ivals,
                   const int* __restrict__ H, const int* __restrict__ Bb,
                   int2* __restrict__ stageE, int2* __restrict__ stageU,
                   float* __restrict__ stageUv) {
    __shared__ int cur[NBKT];
    for (int j = threadIdx.x; j < NBKT; j += 256)
        cur[j] = Bb[j] + H[j * NBLK + blockIdx.x];
    __syncthreads();
    int start = blockIdx.x * IPB;
    int end   = min(start + IPB, TOTAL);
    for (int i = start + threadIdx.x; i < end; i += 256) {
        if (i < N_EDGES) {
            int k   = head[i];
            int pay = tail[i] | ((etype[i] - 1) << 20);
            int pos = atomicAdd(&cur[k >> 8], 1);
            stageE[pos] = make_int2(k, pay);
        } else {
            int ii  = i - N_EDGES;
            int k   = irows[ii];
            int pos = atomicAdd(&cur[NBE + (k >> 8)], 1) - N_EDGES;
            stageU[pos]  = make_int2(k, icols[ii]);
            stageUv[pos] = ivals[ii];
        }
    }
}

// ---------------------------------------------------------------------------
// D: one block per bucket. LDS 256-key histogram + scan -> per-key CSR offsets
// (written to offE/offU), then scatter staged items to final CSR slots.
__global__ __launch_bounds__(256)
void bin_fill(const int* __restrict__ Bb,
              const int2* __restrict__ stageE, const int2* __restrict__ stageU,
              const float* __restrict__ stageUv,
              int* __restrict__ offE, int* __restrict__ offU,
              int* __restrict__ elst, int* __restrict__ ucol,
              float* __restrict__ uval) {
    __shared__ int khist[256];
    __shared__ int cur[256];
    int b = blockIdx.x, t = threadIdx.x;
    khist[t] = 0;
    __syncthreads();
    if (b < NBE) {
        int lo = Bb[b], hi = Bb[b + 1];
        for (int i = lo + t; i < hi; i += 256)
            atomicAdd(&khist[stageE[i].x & 255], 1);
        __syncthreads();
        int v = khist[t];
        for (int d = 1; d < 256; d <<= 1) {
            int u = (t >= d) ? khist[t - d] : 0;
            __syncthreads();
            khist[t] += u;
            __syncthreads();
        }
        int excl = lo + khist[t] - v;
        int key  = b * 256 + t;
        if (key < N_ENTITIES) offE[key] = excl;
        cur[t] = excl;
        __syncthreads();
        for (int i = lo + t; i < hi; i += 256) {
            int2 s = stageE[i];
            int p = atomicAdd(&cur[s.x & 255], 1);
            elst[p] = s.y;
        }
        if (b == 0 && t == 0) offE[N_ENTITIES] = N_EDGES;
    } else {
        int lo = Bb[b] - N_EDGES, hi = Bb[b + 1] - N_EDGES;
        for (int i = lo + t; i < hi; i += 256)
            atomicAdd(&khist[stageU[i].x & 255], 1);
        __syncthreads();
        int v = khist[t];
        for (int d = 1; d < 256; d <<= 1) {
            int u = (t >= d) ? khist[t - d] : 0;
            __syncthreads();
            khist[t] += u;
            __syncthreads();
        }
        int excl = lo + khist[t] - v;
        int key  = (b - NBE) * 256 + t;
        if (key < N_USERS) offU[key] = excl;
        cur[t] = excl;
        __syncthreads();
        for (int i = lo + t; i < hi; i += 256) {
            int2 s = stageU[i];
            float vv = stageUv[i];
            int p = atomicAdd(&cur[s.x & 255], 1);
            ucol[p] = s.y;
            uval[p] = vv;
        }
        if (b == NBE && t == 0) offU[N_USERS] = NNZ;
    }
}

// ---------------------------------------------------------------------------
// Fused per-hop pass: blocks [0,ENT_BLOCKS) do entity rows, rest do users.
template <bool HOP0>
__global__ __launch_bounds__(256)
void hop_pass(const float* __restrict__ ent_in, const float* __restrict__ usr_in,
              const float* __restrict__ weight, const float* __restrict__ latent,
              const float* __restrict__ dw,
              const int* __restrict__ offE, const int* __restrict__ elst,
              const int* __restrict__ offU, const int* __restrict__ ucol,
              const float* __restrict__ uval,
              float* __restrict__ Ae_out, float* __restrict__ Au_out,
              float* __restrict__ ent_res, float* __restrict__ usr_res,
              const float* __restrict__ ent_base, const float* __restrict__ usr_base) {
    __shared__ float w_lds[N_RELM1 * CH];
    int lane = threadIdx.x & 63;
    if (blockIdx.x < ENT_BLOCKS) {
        for (int i = threadIdx.x; i < N_RELM1 * CH; i += 256) w_lds[i] = weight[i];
        __syncthreads();
        int row = blockIdx.x * 4 + (threadIdx.x >> 6);
        int lo = offE[row], hi = offE[row + 1];
        float acc = 0.0f;
        for (int k0 = lo; k0 < hi; k0 += 64) {
            int m = min(64, hi - k0);
            int p = (lane < m) ? elst[k0 + lane] : 0;
            int k = 0;
            for (; k + 3 < m; k += 4) {      // 4 gathers in flight
                int p0 = __shfl(p, k,     64);
                int p1 = __shfl(p, k + 1, 64);
                int p2 = __shfl(p, k + 2, 64);
                int p3 = __shfl(p, k + 3, 64);
                float x0 = ent_in[(p0 & 0xFFFFF) * CH + lane];
                float x1 = ent_in[(p1 & 0xFFFFF) * CH + lane];
                float x2 = ent_in[(p2 & 0xFFFFF) * CH + lane];
                float x3 = ent_in[(p3 & 0xFFFFF) * CH + lane];
                acc += x0 * w_lds[(p0 >> 20) * CH + lane];
                acc += x1 * w_lds[(p1 >> 20) * CH + lane];
                acc += x2 * w_lds[(p2 >> 20) * CH + lane];
                acc += x3 * w_lds[(p3 >> 20) * CH + lane];
            }
            for (; k < m; ++k) {
                int pk = __shfl(p, k, 64);
                acc += ent_in[(pk & 0xFFFFF) * CH + lane] * w_lds[(pk >> 20) * CH + lane];
            }
        }
        float s = waveReduceSum(acc * acc);
        float y = acc / fmaxf(sqrtf(s), 1e-12f);
        int idx = row * CH + lane;
        if (HOP0) { Ae_out[idx] = y; ent_res[idx] = ent_base[idx] + y; }
        else      { ent_res[idx] += y; }
    } else {
        int row = (blockIdx.x - ENT_BLOCKS) * 4 + (threadIdx.x >> 6);
        int idx = row * CH + lane;
        float u  = usr_in[idx];
        float d0 = waveReduceSum(u * latent[0 * CH + lane]);
        float d1 = waveReduceSum(u * latent[1 * CH + lane]);
        float d2 = waveReduceSum(u * latent[2 * CH + lane]);
        float d3 = waveReduceSum(u * latent[3 * CH + lane]);
        float mx = fmaxf(fmaxf(d0, d1), fmaxf(d2, d3));
        float e0 = expf(d0 - mx), e1 = expf(d1 - mx), e2 = expf(d2 - mx), e3 = expf(d3 - mx);
        float inv = 1.0f / (e0 + e1 + e2 + e3);
        float mix = (e0 * dw[0 * CH + lane] + e1 * dw[1 * CH + lane] +
                     e2 * dw[2 * CH + lane] + e3 * dw[3 * CH + lane]) * inv;
        float acc = 0.0f;
        int lo = offU[row], hi = offU[row + 1];
        for (int k0 = lo; k0 < hi; k0 += 64) {
            int m = min(64, hi - k0);
            int   cl = (lane < m) ? ucol[k0 + lane] : 0;
            float vv = (lane < m) ? uval[k0 + lane] : 0.0f;
            int k = 0;
            for (; k + 3 < m; k += 4) {
                int   c0 = __shfl(cl, k,     64);
                int   c1 = __shfl(cl, k + 1, 64);
                int   c2 = __shfl(cl, k + 2, 64);
                int   c3 = __shfl(cl, k + 3, 64);
                float v0 = __shfl(vv, k,     64);
                float v1 = __shfl(vv, k + 1, 64);
                float v2 = __shfl(vv, k + 2, 64);
                float v3 = __shfl(vv, k + 3, 64);
                float x0 = ent_in[c0 * CH + lane];
                float x1 = ent_in[c1 * CH + lane];
                float x2 = ent_in[c2 * CH + lane];
                float x3 = ent_in[c3 * CH + lane];
                acc += v0 * x0; acc += v1 * x1; acc += v2 * x2; acc += v3 * x3;
            }
            for (; k < m; ++k) {
                int   ck = __shfl(cl, k, 64);
                float vk = __shfl(vv, k, 64);
                acc += vk * ent_in[ck * CH + lane];
            }
        }
        float un = acc * (1.0f + mix);
        float s  = waveReduceSum(un * un);
        float y  = un / fmaxf(sqrtf(s), 1e-12f);
        if (HOP0) { Au_out[idx] = y; usr_res[idx] = usr_base[idx] + y; }
        else      { usr_res[idx] += y; }
    }
}

// ---------------------------------------------------------------------------
// Block 0: disen_weight = softmax(att,-1) @ weight (4x8 @ 8x64).
// Block 1: distance-correlation, one wave per factor pair, lane = (r,c) of 8x8.
__global__ __launch_bounds__(384)
void discor_kernel(const float* __restrict__ att,
                   const float* __restrict__ weight,
                   float* __restrict__ dw,
                   float* __restrict__ cor_out) {
    __shared__ float part[6];
    if (blockIdx.x == 0) {
        if (threadIdx.x < 256) {
            int f = threadIdx.x >> 6;
            int c = threadIdx.x & 63;
            float m = -1e30f;
            #pragma unroll
            for (int j = 0; j < N_RELM1; ++j) m = fmaxf(m, att[f * N_RELM1 + j]);
            float s = 0.0f, w[N_RELM1];
            #pragma unroll
            for (int j = 0; j < N_RELM1; ++j) { w[j] = expf(att[f * N_RELM1 + j] - m); s += w[j]; }
            float acc = 0.0f;
            #pragma unroll
            for (int j = 0; j < N_RELM1; ++j) acc += w[j] * weight[j * CH + c];
            dw[f * CH + c] = acc / s;
        }
    } else {
        int w    = threadIdx.x >> 6;   // 0..5 = pair index
        int lane = threadIdx.x & 63;
        const int pi[6] = {0, 0, 0, 1, 1, 2};
        const int pj[6] = {1, 2, 3, 2, 3, 3};
        int r = lane >> 3, c = lane & 7;
        const float* t1 = att + pi[w] * N_RELM1;
        const float* t2 = att + pj[w] * N_RELM1;
        float a  = sqrtf(fmaxf(t1[r] * t1[r] - 2.0f * t1[r] * t1[c] + t1[c] * t1[c], 0.0f) + 1e-8f);
        float bb = sqrtf(fmaxf(t2[r] * t2[r] - 2.0f * t2[r] * t2[c] + t2[c] * t2[c], 0.0f) + 1e-8f);
        float rsA = a, rsB = bb;
        #pragma unroll
        for (int o = 1; o < 8; o <<= 1) { rsA += __shfl_xor(rsA, o, 64); rsB += __shfl_xor(rsB, o, 64); }
        float csA = a, csB = bb;
        #pragma unroll
        for (int o = 8; o < 64; o <<= 1) { csA += __shfl_xor(csA, o, 64); csB += __shfl_xor(csB, o, 64); }
        float totA = rsA, totB = rsB;
        #pragma unroll
        for (int o = 8; o < 64; o <<= 1) { totA += __shfl_xor(totA, o, 64); totB += __shfl_xor(totB, o, 64); }
        float A = a  - csA * 0.125f - rsA * 0.125f + totA * (1.0f / 64.0f);
        float B = bb - csB * 0.125f - rsB * 0.125f + totB * (1.0f / 64.0f);
        float sAB = A * B, sAA = A * A, sBB = B * B;
        #pragma unroll
        for (int o = 1; o < 64; o <<= 1) {
            sAB += __shfl_xor(sAB, o, 64);
            sAA += __shfl_xor(sAA, o, 64);
            sBB += __shfl_xor(sBB, o, 64);
        }
        if (lane == 0) {
            float dAB = sqrtf(fmaxf(sAB * (1.0f / 64.0f), 0.0f) + 1e-8f);
            float dAA = sqrtf(fmaxf(sAA * (1.0f / 64.0f), 0.0f) + 1e-8f);
            float dBB = sqrtf(fmaxf(sBB * (1.0f / 64.0f), 0.0f) + 1e-8f);
            part[w] = dAB / sqrtf(dAA * dBB + 1e-8f);
        }
        __syncthreads();
        if (threadIdx.x == 0) {
            float s = 0.0f;
            for (int q = 0; q < 6; ++q) s += part[q];
            cor_out[0] = s;
        }
    }
}

// ---------------------------------------------------------------------------
extern "C" void kernel_launch(void* const* d_in, const int* in_sizes, int n_in,
                              void* d_out, int out_size, void* d_ws, size_t ws_size,
                              hipStream_t stream) {
    const float* user_emb   = (const float*)d_in[0];
    const float* entity_emb = (const float*)d_in[1];
    const float* latent     = (const float*)d_in[2];
    const float* weight     = (const float*)d_in[3];
    const float* att        = (const float*)d_in[4];
    const float* ivals      = (const float*)d_in[5];
    const int*   head       = (const int*)d_in[6];
    const int*   tail       = (const int*)d_in[7];
    const int*   etype      = (const int*)d_in[8];
    const int*   irows      = (const int*)d_in[9];
    const int*   icols      = (const int*)d_in[10];

    float* out     = (float*)d_out;
    float* ent_res = out;
    float* usr_res = out + (size_t)N_ENTITIES * CH;
    float* cor_out = out + (size_t)N_ENTITIES * CH + (size_t)N_USERS * CH;

    const size_t ENT_ELEMS = (size_t)N_ENTITIES * CH;   // 6.4M
    const size_t USR_ELEMS = (size_t)N_USERS * CH;      // 3.2M

    // Workspace carve-up (~52 MB). Staging aliases Ae (dead until hop 0).
    float* ws   = (float*)d_ws;
    float* Ae   = ws;                               // entity emb after hop0 (25.6 MB)
    float* Au   = Ae + ENT_ELEMS;                   // user emb after hop0 (12.8 MB)
    float* dw   = Au + USR_ELEMS;                   // 4x64 disen weight
    int*   offE = (int*)(dw + N_FACTORS * CH);      // 100001
    int*   offU = offE + N_ENTITIES + 1;            // 50001
    int*   elst = offU + N_USERS + 1;               // 1.5M packed
    int*   ucol = elst + N_EDGES;                   // 800K
    float* uval = (float*)(ucol + NNZ);             // 800K
    int*   H    = (int*)(uval + NNZ);               // NBKT*NBLK = 164947
    int*   T    = H + NBKT * NBLK;                  // 587
    int*   Bb   = T + NBKT;                         // 588
    // Staging aliased on Ae: 1.5M int2 + 800K int2 + 800K float = 21.6 MB < 25.6 MB
    int2*  stageE  = (int2*)Ae;
    int2*  stageU  = ((int2*)Ae) + N_EDGES;
    float* stageUv = (float*)(stageU + NNZ);

    discor_kernel<<<2, 384, 0, stream>>>(att, weight, dw, cor_out);

    // ---- Build CSR (no global atomics, no memsets) ----
    count_coarse<<<NBLK, 256, 0, stream>>>(head, irows, H);
    scan_hcols<<<NBKT, 64, 0, stream>>>(H, T);
    scan_buckets<<<1, 1024, 0, stream>>>(T, Bb);
    scatter_stage<<<NBLK, 256, 0, stream>>>(head, tail, etype, irows, icols, ivals,
                                            H, Bb, stageE, stageU, stageUv);
    bin_fill<<<NBKT, 256, 0, stream>>>(Bb, stageE, stageU, stageUv,
                                       offE, offU, elst, ucol, uval);

    // ---- Hop 0 (reads input embeddings; writes Ae/Au — staging now dead) ----
    hop_pass<true><<<ENT_BLOCKS + USR_BLOCKS, 256, 0, stream>>>(
        entity_emb, user_emb, weight, latent, dw,
        offE, elst, offU, ucol, uval,
        Ae, Au, ent_res, usr_res, entity_emb, user_emb);

    // ---- Hop 1 (reads hop-0 embeddings) ----
    hop_pass<false><<<ENT_BLOCKS + USR_BLOCKS, 256, 0, stream>>>(
        Ae, Au, weight, latent, dw,
        offE, elst, offU, ucol, uval,
        nullptr, nullptr, ent_res, usr_res, nullptr, nullptr);
}

// Round 7
// 399.992 us; speedup vs baseline: 3.0467x; 1.0448x over previous
//
#include <hip/hip_runtime.h>
#include <math.h>

// Problem constants (match reference)
constexpr int CH         = 64;
constexpr int N_USERS    = 50000;
constexpr int N_ENTITIES = 100000;
constexpr int N_FACTORS  = 4;
constexpr int N_RELM1    = 8;     // N_REL - 1
constexpr int N_EDGES    = 1500000;
constexpr int NNZ        = 800000;

constexpr int NBE        = (N_ENTITIES + 255) / 256;  // 391 coarse buckets (E)
constexpr int NBU        = (N_USERS + 255) / 256;     // 196 coarse buckets (U)
constexpr int NBKT       = NBE + NBU;                 // 587
constexpr int TOTAL      = N_EDGES + NNZ;             // 2.3M items
constexpr int IPB        = 8192;                      // items per count/stage block
constexpr int NBLK       = (TOTAL + IPB - 1) / IPB;   // 281
constexpr int ENT_BLOCKS = N_ENTITIES / 4;            // 25000 (exact)
constexpr int USR_BLOCKS = N_USERS / 4;               // 12500 (exact)

typedef unsigned int u32;

// ---------------------------------------------------------------------------
__device__ __forceinline__ u32 pack_bf16x2(float a, float b) {
    u32 ua = __float_as_uint(a), ub = __float_as_uint(b);
    u32 ra = (ua + 0x7FFFu + ((ua >> 16) & 1u)) >> 16;
    u32 rb = (ub + 0x7FFFu + ((ub >> 16) & 1u)) >> 16;
    return ra | (rb << 16);
}
__device__ __forceinline__ float bf_lo(u32 v) { return __uint_as_float(v << 16); }
__device__ __forceinline__ float bf_hi(u32 v) { return __uint_as_float(v & 0xFFFF0000u); }

__device__ __forceinline__ int coarse_bucket(int i, const int* __restrict__ head,
                                             const int* __restrict__ irows) {
    return (i < N_EDGES) ? (head[i] >> 8) : (NBE + (irows[i - N_EDGES] >> 8));
}

// ---------------------------------------------------------------------------
// A: per-block coarse-bucket histogram -> H[bucket * NBLK + block].
__global__ __launch_bounds__(256)
void count_coarse(const int* __restrict__ head, const int* __restrict__ irows,
                  int* __restrict__ H) {
    __shared__ int hist[NBKT];
    for (int j = threadIdx.x; j < NBKT; j += 256) hist[j] = 0;
    __syncthreads();
    int start = blockIdx.x * IPB;
    int end   = min(start + IPB, TOTAL);
    for (int i = start + threadIdx.x; i < end; i += 256)
        atomicAdd(&hist[coarse_bucket(i, head, irows)], 1);
    __syncthreads();
    for (int j = threadIdx.x; j < NBKT; j += 256)
        H[j * NBLK + blockIdx.x] = hist[j];
}

// B1: one wave per bucket — exclusive scan of H[bucket][0..NBLK), total -> T.
__global__ __launch_bounds__(64)
void scan_hcols(int* __restrict__ H, int* __restrict__ T) {
    int b = blockIdx.x, lane = threadIdx.x;
    int carry = 0;
    #pragma unroll
    for (int c = 0; c < (NBLK + 63) / 64; ++c) {
        int idx = c * 64 + lane;
        int v = (idx < NBLK) ? H[b * NBLK + idx] : 0;
        int incl = v;
        #pragma unroll
        for (int d = 1; d < 64; d <<= 1) {
            int u = __shfl_up(incl, d, 64);
            if (lane >= d) incl += u;
        }
        if (idx < NBLK) H[b * NBLK + idx] = carry + incl - v;
        carry += __shfl(incl, 63, 64);
    }
    if (lane == 0) T[b] = carry;
}

// B2: single block — exclusive scan of T -> Bb, sentinel Bb[NBKT].
__global__ __launch_bounds__(1024)
void scan_buckets(const int* __restrict__ T, int* __restrict__ Bb) {
    __shared__ int lds[1024];
    int t = threadIdx.x;
    int v = (t < NBKT) ? T[t] : 0;
    lds[t] = v;
    __syncthreads();
    for (int d = 1; d < 1024; d <<= 1) {
        int u = (t >= d) ? lds[t - d] : 0;
        __syncthreads();
        lds[t] += u;
        __syncthreads();
    }
    if (t < NBKT) Bb[t] = lds[t] - v;
    if (t == NBKT - 1) Bb[NBKT] = lds[t];
}

// ---------------------------------------------------------------------------
// C: partition into coarse buckets; per-block ranges pre-reserved, LDS atomics.
__global__ __launch_bounds__(256)
void scatter_stage(const int* __restrict__ head, const int* __restrict__ tail,
                   const int* __restrict__ etype,
                   const int* __restrict__ irows, const int* __restrict__ icols,
                   const float* __restrict__ ivals,
                   const int* __restrict__ H, const int* __restrict__ Bb,
                   int2* __restrict__ stageE, int2* __restrict__ stageU,
                   float* __restrict__ stageUv) {
    __shared__ int cur[NBKT];
    for (int j = threadIdx.x; j < NBKT; j += 256)
        cur[j] = Bb[j] + H[j * NBLK + blockIdx.x];
    __syncthreads();
    int start = blockIdx.x * IPB;
    int end   = min(start + IPB, TOTAL);
    for (int i = start + threadIdx.x; i < end; i += 256) {
        if (i < N_EDGES) {
            int k   = head[i];
            int pay = tail[i] | ((etype[i] - 1) << 20);
            int pos = atomicAdd(&cur[k >> 8], 1);
            stageE[pos] = make_int2(k, pay);
        } else {
            int ii  = i - N_EDGES;
            int k   = irows[ii];
            int pos = atomicAdd(&cur[NBE + (k >> 8)], 1) - N_EDGES;
            stageU[pos]  = make_int2(k, icols[ii]);
            stageUv[pos] = ivals[ii];
        }
    }
}

// ---------------------------------------------------------------------------
// D: one block per bucket; LDS key-hist + scan -> CSR offsets, scatter to CSR.
__global__ __launch_bounds__(256)
void bin_fill(const int* __restrict__ Bb,
              const int2* __restrict__ stageE, const int2* __restrict__ stageU,
              const float* __restrict__ stageUv,
              int* __restrict__ offE, int* __restrict__ offU,
              int* __restrict__ elst, int* __restrict__ ucol,
              float* __restrict__ uval) {
    __shared__ int khist[256];
    __shared__ int cur[256];
    int b = blockIdx.x, t = threadIdx.x;
    khist[t] = 0;
    __syncthreads();
    if (b < NBE) {
        int lo = Bb[b], hi = Bb[b + 1];
        for (int i = lo + t; i < hi; i += 256)
            atomicAdd(&khist[stageE[i].x & 255], 1);
        __syncthreads();
        int v = khist[t];
        for (int d = 1; d < 256; d <<= 1) {
            int u = (t >= d) ? khist[t - d] : 0;
            __syncthreads();
            khist[t] += u;
            __syncthreads();
        }
        int excl = lo + khist[t] - v;
        int key  = b * 256 + t;
        if (key < N_ENTITIES) offE[key] = excl;
        cur[t] = excl;
        __syncthreads();
        for (int i = lo + t; i < hi; i += 256) {
            int2 s = stageE[i];
            int p = atomicAdd(&cur[s.x & 255], 1);
            elst[p] = s.y;
        }
        if (b == 0 && t == 0) offE[N_ENTITIES] = N_EDGES;
    } else {
        int lo = Bb[b] - N_EDGES, hi = Bb[b + 1] - N_EDGES;
        for (int i = lo + t; i < hi; i += 256)
            atomicAdd(&khist[stageU[i].x & 255], 1);
        __syncthreads();
        int v = khist[t];
        for (int d = 1; d < 256; d <<= 1) {
            int u = (t >= d) ? khist[t - d] : 0;
            __syncthreads();
            khist[t] += u;
            __syncthreads();
        }
        int excl = lo + khist[t] - v;
        int key  = (b - NBE) * 256 + t;
        if (key < N_USERS) offU[key] = excl;
        cur[t] = excl;
        __syncthreads();
        for (int i = lo + t; i < hi; i += 256) {
            int2 s = stageU[i];
            float vv = stageUv[i];
            int p = atomicAdd(&cur[s.x & 255], 1);
            ucol[p] = s.y;
            uval[p] = vv;
        }
        if (b == NBE && t == 0) offU[N_USERS] = NNZ;
    }
}

// ---------------------------------------------------------------------------
// Convert fp32 table -> packed bf16x2 (u32 per channel pair).
__global__ __launch_bounds__(256)
void to_bf16(const float* __restrict__ src, u32* __restrict__ dst, int n2) {
    int i = blockIdx.x * 256 + threadIdx.x;
    if (i < n2) {
        float2 f = ((const float2*)src)[i];
        dst[i] = pack_bf16x2(f.x, f.y);
    }
}

// ---------------------------------------------------------------------------
// Fused per-hop pass, bf16 gather table. Wave = 1 row; half-wave = 1 edge
// (lane handles 2 channels via one u32 load); 2 edges per issue, 4 in flight.
template <bool HOP0>
__global__ __launch_bounds__(256)
void hop_pass(const u32* __restrict__ entB,       // bf16x2 entity table (gathered)
              const float* __restrict__ usr_in,   // fp32 user emb (dense)
              const float* __restrict__ weight, const float* __restrict__ latent,
              const float* __restrict__ dw,
              const int* __restrict__ offE, const int* __restrict__ elst,
              const int* __restrict__ offU, const int* __restrict__ ucol,
              const float* __restrict__ uval,
              u32* __restrict__ AeB_out,          // bf16x2 entity out (hop0)
              float* __restrict__ Au_out,         // fp32 user out (hop0)
              float* __restrict__ ent_res, float* __restrict__ usr_res,
              const float* __restrict__ ent_base, const float* __restrict__ usr_base) {
    __shared__ float2 w_lds[N_RELM1 * 32];
    int lane = threadIdx.x & 63;
    int half = lane >> 5;          // which edge of the pair
    int c2   = lane & 31;          // channel pair: channels 2*c2, 2*c2+1
    if (blockIdx.x < ENT_BLOCKS) {
        if (threadIdx.x < N_RELM1 * 32)
            w_lds[threadIdx.x] = ((const float2*)weight)[threadIdx.x];
        __syncthreads();
        int row = blockIdx.x * 4 + (threadIdx.x >> 6);
        int lo = offE[row], hi = offE[row + 1];
        float a0 = 0.0f, a1 = 0.0f;
        for (int k0 = lo; k0 < hi; k0 += 64) {
            int m = min(64, hi - k0);
            int p = (lane < m) ? elst[k0 + lane] : 0;
            int k = 0;
            for (; k + 3 < m; k += 4) {          // 4 edges: 2 per half-wave
                int pA = __shfl(p, k + half,     64);
                int pB = __shfl(p, k + 2 + half, 64);
                u32 xA = entB[(pA & 0xFFFFF) * 32 + c2];
                u32 xB = entB[(pB & 0xFFFFF) * 32 + c2];
                float2 wA = w_lds[(pA >> 20) * 32 + c2];
                float2 wB = w_lds[(pB >> 20) * 32 + c2];
                a0 += bf_lo(xA) * wA.x; a1 += bf_hi(xA) * wA.y;
                a0 += bf_lo(xB) * wB.x; a1 += bf_hi(xB) * wB.y;
            }
            for (; k < m; k += 2) {
                int kk = min(k + half, m - 1);
                float flag = (k + half < m) ? 1.0f : 0.0f;
                int pA = __shfl(p, kk, 64);
                u32 xA = entB[(pA & 0xFFFFF) * 32 + c2];
                float2 wA = w_lds[(pA >> 20) * 32 + c2];
                a0 += flag * bf_lo(xA) * wA.x;
                a1 += flag * bf_hi(xA) * wA.y;
            }
        }
        a0 += __shfl_xor(a0, 32, 64);            // combine edge halves
        a1 += __shfl_xor(a1, 32, 64);
        float s = a0 * a0 + a1 * a1;
        #pragma unroll
        for (int o = 1; o < 32; o <<= 1) s += __shfl_xor(s, o, 64);
        float inv = 1.0f / fmaxf(sqrtf(s), 1e-12f);
        float y0 = a0 * inv, y1 = a1 * inv;
        if (half == 0) {
            int idx = row * 32 + c2;
            if (HOP0) {
                AeB_out[idx] = pack_bf16x2(y0, y1);
                float2 base = ((const float2*)ent_base)[idx];
                ((float2*)ent_res)[idx] = make_float2(base.x + y0, base.y + y1);
            } else {
                float2 r = ((float2*)ent_res)[idx];
                ((float2*)ent_res)[idx] = make_float2(r.x + y0, r.y + y1);
            }
        }
    } else {
        int row = (blockIdx.x - ENT_BLOCKS) * 4 + (threadIdx.x >> 6);
        int idx = row * 32 + c2;
        float2 u  = ((const float2*)usr_in)[idx];
        float2 l0 = ((const float2*)latent)[0 * 32 + c2];
        float2 l1 = ((const float2*)latent)[1 * 32 + c2];
        float2 l2 = ((const float2*)latent)[2 * 32 + c2];
        float2 l3 = ((const float2*)latent)[3 * 32 + c2];
        float d0 = u.x * l0.x + u.y * l0.y;
        float d1 = u.x * l1.x + u.y * l1.y;
        float d2 = u.x * l2.x + u.y * l2.y;
        float d3 = u.x * l3.x + u.y * l3.y;
        #pragma unroll
        for (int o = 1; o < 32; o <<= 1) {
            d0 += __shfl_xor(d0, o, 64); d1 += __shfl_xor(d1, o, 64);
            d2 += __shfl_xor(d2, o, 64); d3 += __shfl_xor(d3, o, 64);
        }
        float mx = fmaxf(fmaxf(d0, d1), fmaxf(d2, d3));
        float e0 = expf(d0 - mx), e1 = expf(d1 - mx), e2 = expf(d2 - mx), e3 = expf(d3 - mx);
        float sinv = 1.0f / (e0 + e1 + e2 + e3);
        float2 w0 = ((const float2*)dw)[0 * 32 + c2];
        float2 w1 = ((const float2*)dw)[1 * 32 + c2];
        float2 w2 = ((const float2*)dw)[2 * 32 + c2];
        float2 w3 = ((const float2*)dw)[3 * 32 + c2];
        float mix0 = (e0 * w0.x + e1 * w1.x + e2 * w2.x + e3 * w3.x) * sinv;
        float mix1 = (e0 * w0.y + e1 * w1.y + e2 * w2.y + e3 * w3.y) * sinv;
        float a0 = 0.0f, a1 = 0.0f;
        int lo = offU[row], hi = offU[row + 1];
        for (int k0 = lo; k0 < hi; k0 += 64) {
            int m = min(64, hi - k0);
            int   cl = (lane < m) ? ucol[k0 + lane] : 0;
            float vv = (lane < m) ? uval[k0 + lane] : 0.0f;
            int k = 0;
            for (; k + 3 < m; k += 4) {
                int   cA = __shfl(cl, k + half,     64);
                int   cB = __shfl(cl, k + 2 + half, 64);
                float vA = __shfl(vv, k + half,     64);
                float vB = __shfl(vv, k + 2 + half, 64);
                u32 xA = entB[cA * 32 + c2];
                u32 xB = entB[cB * 32 + c2];
                a0 += vA * bf_lo(xA); a1 += vA * bf_hi(xA);
                a0 += vB * bf_lo(xB); a1 += vB * bf_hi(xB);
            }
            for (; k < m; k += 2) {
                int kk = min(k + half, m - 1);
                float flag = (k + half < m) ? 1.0f : 0.0f;
                int   cA = __shfl(cl, kk, 64);
                float vA = __shfl(vv, kk, 64) * flag;
                u32 xA = entB[cA * 32 + c2];
                a0 += vA * bf_lo(xA); a1 += vA * bf_hi(xA);
            }
        }
        a0 += __shfl_xor(a0, 32, 64);
        a1 += __shfl_xor(a1, 32, 64);
        float un0 = a0 * (1.0f + mix0);
        float un1 = a1 * (1.0f + mix1);
        float s = un0 * un0 + un1 * un1;
        #pragma unroll
        for (int o = 1; o < 32; o <<= 1) s += __shfl_xor(s, o, 64);
        float inv = 1.0f / fmaxf(sqrtf(s), 1e-12f);
        float y0 = un0 * inv, y1 = un1 * inv;
        if (half == 0) {
            if (HOP0) {
                ((float2*)Au_out)[idx] = make_float2(y0, y1);
                float2 base = ((const float2*)usr_base)[idx];
                ((float2*)usr_res)[idx] = make_float2(base.x + y0, base.y + y1);
            } else {
                float2 r = ((float2*)usr_res)[idx];
                ((float2*)usr_res)[idx] = make_float2(r.x + y0, r.y + y1);
            }
        }
    }
}

// ---------------------------------------------------------------------------
// Block 0: disen_weight = softmax(att,-1) @ weight (4x8 @ 8x64).
// Block 1: distance-correlation, one wave per factor pair.
__global__ __launch_bounds__(384)
void discor_kernel(const float* __restrict__ att,
                   const float* __restrict__ weight,
                   float* __restrict__ dw,
                   float* __restrict__ cor_out) {
    __shared__ float part[6];
    if (blockIdx.x == 0) {
        if (threadIdx.x < 256) {
            int f = threadIdx.x >> 6;
            int c = threadIdx.x & 63;
            float m = -1e30f;
            #pragma unroll
            for (int j = 0; j < N_RELM1; ++j) m = fmaxf(m, att[f * N_RELM1 + j]);
            float s = 0.0f, w[N_RELM1];
            #pragma unroll
            for (int j = 0; j < N_RELM1; ++j) { w[j] = expf(att[f * N_RELM1 + j] - m); s += w[j]; }
            float acc = 0.0f;
            #pragma unroll
            for (int j = 0; j < N_RELM1; ++j) acc += w[j] * weight[j * CH + c];
            dw[f * CH + c] = acc / s;
        }
    } else {
        int w    = threadIdx.x >> 6;   // 0..5 = pair index
        int lane = threadIdx.x & 63;
        const int pi[6] = {0, 0, 0, 1, 1, 2};
        const int pj[6] = {1, 2, 3, 2, 3, 3};
        int r = lane >> 3, c = lane & 7;
        const float* t1 = att + pi[w] * N_RELM1;
        const float* t2 = att + pj[w] * N_RELM1;
        float a  = sqrtf(fmaxf(t1[r] * t1[r] - 2.0f * t1[r] * t1[c] + t1[c] * t1[c], 0.0f) + 1e-8f);
        float bb = sqrtf(fmaxf(t2[r] * t2[r] - 2.0f * t2[r] * t2[c] + t2[c] * t2[c], 0.0f) + 1e-8f);
        float rsA = a, rsB = bb;
        #pragma unroll
        for (int o = 1; o < 8; o <<= 1) { rsA += __shfl_xor(rsA, o, 64); rsB += __shfl_xor(rsB, o, 64); }
        float csA = a, csB = bb;
        #pragma unroll
        for (int o = 8; o < 64; o <<= 1) { csA += __shfl_xor(csA, o, 64); csB += __shfl_xor(csB, o, 64); }
        float totA = rsA, totB = rsB;
        #pragma unroll
        for (int o = 8; o < 64; o <<= 1) { totA += __shfl_xor(totA, o, 64); totB += __shfl_xor(totB, o, 64); }
        float A = a  - csA * 0.125f - rsA * 0.125f + totA * (1.0f / 64.0f);
        float B = bb - csB * 0.125f - rsB * 0.125f + totB * (1.0f / 64.0f);
        float sAB = A * B, sAA = A * A, sBB = B * B;
        #pragma unroll
        for (int o = 1; o < 64; o <<= 1) {
            sAB += __shfl_xor(sAB, o, 64);
            sAA += __shfl_xor(sAA, o, 64);
            sBB += __shfl_xor(sBB, o, 64);
        }
        if (lane == 0) {
            float dAB = sqrtf(fmaxf(sAB * (1.0f / 64.0f), 0.0f) + 1e-8f);
            float dAA = sqrtf(fmaxf(sAA * (1.0f / 64.0f), 0.0f) + 1e-8f);
            float dBB = sqrtf(fmaxf(sBB * (1.0f / 64.0f), 0.0f) + 1e-8f);
            part[w] = dAB / sqrtf(dAA * dBB + 1e-8f);
        }
        __syncthreads();
        if (threadIdx.x == 0) {
            float s = 0.0f;
            for (int q = 0; q < 6; ++q) s += part[q];
            cor_out[0] = s;
        }
    }
}

// ---------------------------------------------------------------------------
extern "C" void kernel_launch(void* const* d_in, const int* in_sizes, int n_in,
                              void* d_out, int out_size, void* d_ws, size_t ws_size,
                              hipStream_t stream) {
    const float* user_emb   = (const float*)d_in[0];
    const float* entity_emb = (const float*)d_in[1];
    const float* latent     = (const float*)d_in[2];
    const float* weight     = (const float*)d_in[3];
    const float* att        = (const float*)d_in[4];
    const float* ivals      = (const float*)d_in[5];
    const int*   head       = (const int*)d_in[6];
    const int*   tail       = (const int*)d_in[7];
    const int*   etype      = (const int*)d_in[8];
    const int*   irows      = (const int*)d_in[9];
    const int*   icols      = (const int*)d_in[10];

    float* out     = (float*)d_out;
    float* ent_res = out;
    float* usr_res = out + (size_t)N_ENTITIES * CH;
    float* cor_out = out + (size_t)N_ENTITIES * CH + (size_t)N_USERS * CH;

    const size_t ENT_ELEMS = (size_t)N_ENTITIES * CH;   // 6.4M
    const size_t USR_ELEMS = (size_t)N_USERS * CH;      // 3.2M
    const int    ENT_PAIRS = (int)(ENT_ELEMS / 2);      // 3.2M u32

    // Workspace carve-up (~52 MB).
    // Region R: [entB | AeB] (25.6 MB) — aliased by the CSR staging arrays
    // (21.6 MB), which are dead before to_bf16/hop0 write entB/AeB.
    float* ws   = (float*)d_ws;
    u32*   entB = (u32*)ws;                         // 3.2M u32 (12.8 MB)
    u32*   AeB  = entB + ENT_PAIRS;                 // 3.2M u32 (12.8 MB)
    float* Au   = (float*)(AeB + ENT_PAIRS);        // 3.2M f32 (12.8 MB)
    float* dw   = Au + USR_ELEMS;                   // 4x64
    int*   offE = (int*)(dw + N_FACTORS * CH);      // 100001
    int*   offU = offE + N_ENTITIES + 1;            // 50001
    int*   elst = offU + N_USERS + 1;               // 1.5M packed
    int*   ucol = elst + N_EDGES;                   // 800K
    float* uval = (float*)(ucol + NNZ);             // 800K
    int*   H    = (int*)(uval + NNZ);               // NBKT*NBLK = 164947
    int*   T    = H + NBKT * NBLK;                  // 587
    int*   Bb   = T + NBKT;                         // 588
    // Staging aliased on R: 1.5M int2 + 800K int2 + 800K f32 = 21.6 MB < 25.6 MB
    int2*  stageE  = (int2*)entB;
    int2*  stageU  = ((int2*)entB) + N_EDGES;
    float* stageUv = (float*)(stageU + NNZ);

    discor_kernel<<<2, 384, 0, stream>>>(att, weight, dw, cor_out);

    // ---- Build CSR (no global atomics, no memsets) ----
    count_coarse<<<NBLK, 256, 0, stream>>>(head, irows, H);
    scan_hcols<<<NBKT, 64, 0, stream>>>(H, T);
    scan_buckets<<<1, 1024, 0, stream>>>(T, Bb);
    scatter_stage<<<NBLK, 256, 0, stream>>>(head, tail, etype, irows, icols, ivals,
                                            H, Bb, stageE, stageU, stageUv);
    bin_fill<<<NBKT, 256, 0, stream>>>(Bb, stageE, stageU, stageUv,
                                       offE, offU, elst, ucol, uval);

    // ---- Convert gather table to bf16 (staging now dead) ----
    to_bf16<<<(ENT_PAIRS + 255) / 256, 256, 0, stream>>>(entity_emb, entB, ENT_PAIRS);

    // ---- Hop 0 (gathers entB; writes AeB bf16 + Au fp32 + residuals) ----
    hop_pass<true><<<ENT_BLOCKS + USR_BLOCKS, 256, 0, stream>>>(
        entB, user_emb, weight, latent, dw,
        offE, elst, offU, ucol, uval,
        AeB, Au, ent_res, usr_res, entity_emb, user_emb);

    // ---- Hop 1 (gathers AeB) ----
    hop_pass<false><<<ENT_BLOCKS + USR_BLOCKS, 256, 0, stream>>>(
        AeB, Au, weight, latent, dw,
        offE, elst, offU, ucol, uval,
        nullptr, nullptr, ent_res, usr_res, nullptr, nullptr);
}